// Round 8
// baseline (228.556 us; speedup 1.0000x reference)
//
#include <hip/hip_runtime.h>

#define N_SP 16384
#define C_DIM 128
#define K_DIM 32
#define TILEN 256                 // n per block
#define NBX   (N_SP / TILEN)      // 64 blocks along n

typedef short short8 __attribute__((ext_vector_type(8)));
typedef float f32x16 __attribute__((ext_vector_type(16)));

__device__ __forceinline__ unsigned f2bfu(float f){
    return (__float_as_uint(f) + 0x8000u) >> 16;   // cheap RN to bf16 bits
}
__device__ __forceinline__ unsigned short f2bf(float f){
    return (unsigned short)f2bfu(f);
}

// swizzled index into a [row][256] ushort tile: XOR n-bits 3..6 with row&15
// -> 8-ushort (16B) groups stay contiguous (b128 legal), rows spread over banks
#define SWZ(row, n) (((row) << 8) + ((n) ^ (((row) & 15) << 3)))

union FragU { int i[4]; short8 s; };

// S-MFMA B-fragment: 8 c-elems of column `col` gathered from xs (R6-proven)
#define S_GROUP(KS, G, SACC) do {                                          \
    const int col_ = 32*(G) + l31;                                         \
    FragU f_;                                                              \
    _Pragma("unroll")                                                      \
    for (int d_ = 0; d_ < 4; ++d_){                                        \
        const int c0_ = (KS)*16 + hi*8 + 2*d_;                             \
        const unsigned lo_  = xs[SWZ(c0_,     col_)];                      \
        const unsigned h16_ = xs[SWZ(c0_ + 1, col_)];                      \
        f_.i[d_] = (int)(lo_ | (h16_ << 16));                              \
    }                                                                      \
    SACC = __builtin_amdgcn_mfma_f32_32x32x16_bf16(cwA[(KS)], f_.s, SACC, 0,0,0); \
} while (0)

__global__ __launch_bounds__(256, 2) void enc_main(
    const float* __restrict__ x,              // [B][C][N]
    const unsigned short* __restrict__ cwt2b, // [K][C] bf16 of -2*scale[k]*cw[k][c]
    const float* __restrict__ combo,          // [K][2] = {scale[k], scale[k]*||cw_k||^2}
    float* __restrict__ wxacc,                // [B][K][C] (zeroed)
    float* __restrict__ wsacc)                // [B][K]    (zeroed)
{
    __shared__ unsigned short xs[C_DIM * TILEN];   // bf16 x[c][n'] swizzled (64 KB)
    __shared__ unsigned short aws[K_DIM * TILEN];  // bf16 aw[k][n'] (16 KB);
                                                   // first 4 KB doubles as x2 partials
    const int t   = threadIdx.x;   // 0..255
    const int b   = blockIdx.y;
    const int w   = t >> 6;        // wave 0..3
    const int ln  = t & 63;
    const int hi  = (t >> 5) & 1;
    const int l31 = t & 31;

    const float* xb = x + (size_t)b * C_DIM * N_SP;
    const int n0 = blockIdx.x * TILEN;

    // held codeword A-fragments: lane l31 = k-row, hi picks 8-c half of each 16-chunk
    short8 cwA[8];
#pragma unroll
    for (int ksg = 0; ksg < 8; ++ksg)
        cwA[ksg] = *(const short8*)(const void*)(cwt2b + l31 * C_DIM + ksg * 16 + hi * 8);

    short8 ones;
#pragma unroll
    for (int i = 0; i < 8; ++i) ones[i] = (short)0x3F80;  // bf16 1.0

    // ---- load phase: wave w streams c-rows 32w..32w+31; 1KB contiguous PER INSTR ----
    float* x2pf = (float*)aws;                 // [4 waves][TILEN] fp32 partial x2
    const float* xq = xb + n0 + 4 * ln;        // lane ln owns n-cols 4ln..4ln+3
    const int cbase = 32 * w;

    float p0 = 0.f, p1 = 0.f, p2 = 0.f, p3 = 0.f;
    float4 cur[4], nxt[4];
#pragma unroll
    for (int j = 0; j < 4; ++j)
        cur[j] = *(const float4*)(xq + (size_t)(cbase + j) * N_SP);

#pragma unroll 1
    for (int r = 0; r < 32; r += 4){
        if (r < 28){
#pragma unroll
            for (int j = 0; j < 4; ++j)
                nxt[j] = *(const float4*)(xq + (size_t)(cbase + r + 4 + j) * N_SP);
        }
#pragma unroll
        for (int j = 0; j < 4; ++j){
            const int c = cbase + r + j;
            const float4 v = cur[j];
            p0 = fmaf(v.x, v.x, p0);
            p1 = fmaf(v.y, v.y, p1);
            p2 = fmaf(v.z, v.z, p2);
            p3 = fmaf(v.w, v.w, p3);
            uint2 uu;
            uu.x = f2bfu(v.x) | (f2bfu(v.y) << 16);
            uu.y = f2bfu(v.z) | (f2bfu(v.w) << 16);
            *(uint2*)&xs[SWZ(c, 4 * ln)] = uu;   // 8B, inside one 16B swizzle group
        }
#pragma unroll
        for (int j = 0; j < 4; ++j) cur[j] = nxt[j];
    }
    {
        float4 pp; pp.x = p0; pp.y = p1; pp.z = p2; pp.w = p3;
        *(float4*)&x2pf[w * TILEN + 4 * ln] = pp;   // exact fp32 partials
    }

    __syncthreads();   // xs + x2 partials complete (all waves)

    // exact x2 for this thread's two columns (cross-wave sum of partials)
    const int col0 = 64 * w + l31;
    const int col1 = col0 + 32;
    const float x2g0 = x2pf[col0] + x2pf[TILEN + col0] + x2pf[2*TILEN + col0] + x2pf[3*TILEN + col0];
    const float x2g1 = x2pf[col1] + x2pf[TILEN + col1] + x2pf[2*TILEN + col1] + x2pf[3*TILEN + col1];

    __syncthreads();   // ALL x2 reads done -> aws region may be overwritten

    // ---- S phase: S[k][n] = cwt2 * x via MFMA, B-frags gathered from xs ----
    f32x16 sA, sB;     // wave w owns col-groups 2w (cols col0-range), 2w+1
#pragma unroll
    for (int i = 0; i < 16; ++i){ sA[i] = 0.f; sB[i] = 0.f; }
#pragma unroll
    for (int ks = 0; ks < 8; ++ks){
        S_GROUP(ks, 2 * w,     sA);
        S_GROUP(ks, 2 * w + 1, sB);
    }

    // ---- softmax over k on the MFMA D-layout ----
    float csx[16], csy[16];
#pragma unroll
    for (int q = 0; q < 16; ++q){
        const int row = (q & 3) + 8 * (q >> 2) + 4 * hi;
        csx[q] = combo[2 * row];
        csy[q] = combo[2 * row + 1];
    }
    {   // group 2w: cols col0
        float arg[16]; float ml = -3.4e38f;
#pragma unroll
        for (int q = 0; q < 16; ++q){
            arg[q] = fmaf(csx[q], x2g0, sA[q] + csy[q]);
            ml = fmaxf(ml, arg[q]);
        }
        const float mm = fmaxf(ml, __shfl_xor(ml, 32));
        float sum = 0.f;
#pragma unroll
        for (int q = 0; q < 16; ++q){ float p = __expf(arg[q] - mm); arg[q] = p; sum += p; }
        sum += __shfl_xor(sum, 32);
        const float r = 1.f / sum;
#pragma unroll
        for (int q = 0; q < 16; ++q){
            const int row = (q & 3) + 8 * (q >> 2) + 4 * hi;
            aws[SWZ(row, col0)] = f2bf(arg[q] * r);
        }
    }
    {   // group 2w+1: cols col1
        float arg[16]; float ml = -3.4e38f;
#pragma unroll
        for (int q = 0; q < 16; ++q){
            arg[q] = fmaf(csx[q], x2g1, sB[q] + csy[q]);
            ml = fmaxf(ml, arg[q]);
        }
        const float mm = fmaxf(ml, __shfl_xor(ml, 32));
        float sum = 0.f;
#pragma unroll
        for (int q = 0; q < 16; ++q){ float p = __expf(arg[q] - mm); arg[q] = p; sum += p; }
        sum += __shfl_xor(sum, 32);
        const float r = 1.f / sum;
#pragma unroll
        for (int q = 0; q < 16; ++q){
            const int row = (q & 3) + 8 * (q >> 2) + 4 * hi;
            aws[SWZ(row, col1)] = f2bf(arg[q] * r);
        }
    }

    __syncthreads();   // aws complete

    // ---- phase D: wx[k][c] += aw[k][n] * x[n][c]; wave w owns c-strip 32w.. ----
    f32x16 acc, accS;
#pragma unroll
    for (int i = 0; i < 16; ++i){ acc[i] = 0.f; accS[i] = 0.f; }
    const int cmy = 32 * w + l31;

#pragma unroll
    for (int ks = 0; ks < 16; ++ks){           // n = 256 -> 16 k-steps of 16
        const int n8 = ks * 16 + hi * 8;
        short8 af = *(const short8*)(const void*)&aws[SWZ(l31, n8)];
        short8 bf = *(const short8*)(const void*)&xs[SWZ(cmy, n8)];
        acc = __builtin_amdgcn_mfma_f32_32x32x16_bf16(af, bf, acc, 0, 0, 0);
        if ((ks >> 2) == w)                    // wsum: wave w covers ks 4w..4w+3
            accS = __builtin_amdgcn_mfma_f32_32x32x16_bf16(af, ones, accS, 0, 0, 0);
    }

    // ---- epilogue: atomic-reduce block partials to global ----
    float* wxb = wxacc + (size_t)b * K_DIM * C_DIM;
#pragma unroll
    for (int rg = 0; rg < 16; ++rg){
        const int row = (rg & 3) + 8 * (rg >> 2) + 4 * hi;  // verified D layout
        atomicAdd(&wxb[row * C_DIM + cmy], acc[rg]);
    }
    if (l31 == 0){
#pragma unroll
        for (int rg = 0; rg < 16; ++rg){
            const int row = (rg & 3) + 8 * (rg >> 2) + 4 * hi;
            atomicAdd(&wsacc[b * K_DIM + row], accS[rg]);
        }
    }
}

__global__ void enc_zero(float* __restrict__ p, int n){
    const int i = blockIdx.x * 256 + threadIdx.x;
    if (i < n) p[i] = 0.f;
}

__global__ void enc_prep(const float* __restrict__ cw, const float* __restrict__ scale,
                         unsigned short* __restrict__ cwt2b, float* __restrict__ combo){
    const int t = threadIdx.x;  // 128 threads; t = c
    for (int k = 0; k < K_DIM; ++k)
        cwt2b[k * C_DIM + t] = f2bf(-2.f * scale[k] * cw[k * C_DIM + t]);
    if (t < K_DIM){
        float s = 0.f;
        for (int c = 0; c < C_DIM; ++c){
            float v = cw[t * C_DIM + c];
            s = fmaf(v, v, s);
        }
        combo[2 * t]     = scale[t];
        combo[2 * t + 1] = scale[t] * s;
    }
}

__global__ void enc_final(const float* __restrict__ wxacc, const float* __restrict__ wsacc,
                          const float* __restrict__ cw, float* __restrict__ out){
    const int i  = blockIdx.x * 256 + threadIdx.x;  // B*K*C = 131072
    const int c  = i & (C_DIM - 1);
    const int kk = (i >> 7) & (K_DIM - 1);
    const int bk = i >> 7;
    out[i] = wxacc[i] - wsacc[bk] * cw[kk * C_DIM + c];
}

extern "C" void kernel_launch(void* const* d_in, const int* in_sizes, int n_in,
                              void* d_out, int out_size, void* d_ws, size_t ws_size,
                              hipStream_t stream){
    (void)in_sizes; (void)n_in; (void)out_size; (void)ws_size;
    const float* x     = (const float*)d_in[0];
    const float* cw    = (const float*)d_in[1];
    const float* scale = (const float*)d_in[2];
    float* out = (float*)d_out;

    float* wxacc = (float*)d_ws;                            // 131072 f32
    float* wsacc = wxacc + 32 * 32 * C_DIM;                 // 1024 f32
    float* combo = wsacc + 32 * 32;                         // 64 f32
    unsigned short* cwt2b = (unsigned short*)(combo + 64);  // 4096 ushort

    const int nz = 32 * 32 * C_DIM + 32 * 32;
    enc_zero<<<(nz + 255) / 256, 256, 0, stream>>>(wxacc, nz);
    enc_prep<<<1, 128, 0, stream>>>(cw, scale, cwt2b, combo);
    enc_main<<<dim3(NBX, 32), 256, 0, stream>>>(x, cwt2b, combo, wxacc, wsacc);
    enc_final<<<512, 256, 0, stream>>>(wxacc, wsacc, cw, out);
}